// Round 1
// baseline (225.635 us; speedup 1.0000x reference)
//
#include <hip/hip_runtime.h>

typedef unsigned short u16;
typedef unsigned int u32;
typedef __attribute__((ext_vector_type(8))) short short8;
typedef __attribute__((ext_vector_type(4))) float f32x4;

#define S_LEN 2048
#define D_DIM 1024
#define NH    16
#define DH    64
#define B_SZ  2
#define M_ROWS (B_SZ * S_LEN)   // 4096

// ---------- helpers ----------
__device__ __forceinline__ u16 f2bf(float f) {
  u32 u = __float_as_uint(f);
  u += 0x7FFFu + ((u >> 16) & 1u);   // RNE
  return (u16)(u >> 16);
}
__device__ __forceinline__ float bf2f(u16 u) {
  return __uint_as_float(((u32)u) << 16);
}

__device__ __forceinline__ void gll16(const void* g, void* l) {
  __builtin_amdgcn_global_load_lds((const __attribute__((address_space(1))) u32*)g,
                                   (__attribute__((address_space(3))) u32*)l,
                                   16, 0, 0);
}

// ---------- elementwise conversion fp32 -> bf16 ----------
__global__ __launch_bounds__(256) void cvt_bf16(const float* __restrict__ src,
                                                u16* __restrict__ dst, int n4) {
  int i = blockIdx.x * 256 + threadIdx.x;
  if (i >= n4) return;
  const float4 v = ((const float4*)src)[i];
  u32 lo = (u32)f2bf(v.x) | ((u32)f2bf(v.y) << 16);
  u32 hi = (u32)f2bf(v.z) | ((u32)f2bf(v.w) << 16);
  ((u32*)dst)[2 * i]     = lo;
  ((u32*)dst)[2 * i + 1] = hi;
}

// ---------- RoPE cos/sin table: tab[s][j] for j in [0,32) ----------
__global__ __launch_bounds__(256) void rope_tab(float2* __restrict__ tab) {
  int i = blockIdx.x * 256 + threadIdx.x;   // S_LEN*32 entries
  int s = i >> 5, j = i & 31;
  float inv = exp2f(-(float)j * (13.287712379549449f / 32.f)); // 10000^(-j/32)
  float fr = (float)s * inv;
  tab[i] = make_float2(cosf(fr), sinf(fr));
}

// ---------- shared 128x128-tile GEMM core: C = A[M,K] * W[N,K]^T ----------
// A, W row-major with row stride D_DIM; K = D_DIM; BK = 64; 4 waves (2x2 of 64x64).
__device__ __forceinline__ void gemm128_core(const u16* __restrict__ A,
                                             const u16* __restrict__ W,
                                             int m0, int n0,
                                             u16* As, u16* Bs,
                                             f32x4 acc[4][4]) {
  const int tid  = threadIdx.x;
  const int lane = tid & 63;
  const int wr   = (tid >> 6) >> 1;
  const int wc   = (tid >> 6) & 1;
  const int l15  = lane & 15;
  const int l4   = lane >> 4;

  #pragma unroll
  for (int m = 0; m < 4; ++m)
    #pragma unroll
    for (int n = 0; n < 4; ++n)
      acc[m][n] = (f32x4){0.f, 0.f, 0.f, 0.f};

  for (int kt = 0; kt < D_DIM / 64; ++kt) {
    const int k0 = kt * 64;
    #pragma unroll
    for (int i = 0; i < 4; ++i) {
      int c = tid + i * 256;            // chunk id: 1024 chunks of 16B per tile
      int row = c >> 3, ch = c & 7;
      gll16(A + (size_t)(m0 + row) * D_DIM + k0 + ch * 8, As + c * 8);
      gll16(W + (size_t)(n0 + row) * D_DIM + k0 + ch * 8, Bs + c * 8);
    }
    __syncthreads();   // drains vmcnt (global_load_lds) before reads
    #pragma unroll
    for (int kk = 0; kk < 2; ++kk) {
      short8 av[4], bv[4];
      #pragma unroll
      for (int m = 0; m < 4; ++m)
        av[m] = *(const short8*)(As + (wr * 64 + m * 16 + l15) * 64 + kk * 32 + l4 * 8);
      #pragma unroll
      for (int n = 0; n < 4; ++n)
        bv[n] = *(const short8*)(Bs + (wc * 64 + n * 16 + l15) * 64 + kk * 32 + l4 * 8);
      #pragma unroll
      for (int m = 0; m < 4; ++m)
        #pragma unroll
        for (int n = 0; n < 4; ++n)
          acc[m][n] = __builtin_amdgcn_mfma_f32_16x16x32_bf16(av[m], bv[n], acc[m][n], 0, 0, 0);
    }
    __syncthreads();   // all reads done before next-tile staging
  }
}

// ---------- fused projection: q(+rope), k(+rope), v(->transposed), g(silu) ----------
__global__ __launch_bounds__(256) void proj_kernel(
    const u16* __restrict__ xb,
    const u16* __restrict__ wqb, const u16* __restrict__ wkb,
    const u16* __restrict__ wvb, const u16* __restrict__ wgb,
    u16* __restrict__ qb, u16* __restrict__ kb,
    u16* __restrict__ vT, u16* __restrict__ gb,
    const float2* __restrict__ rope)
{
  __shared__ u16 As[128 * 64];
  __shared__ u16 Bs[128 * 64];
  const int z  = blockIdx.z;
  const u16* W = (z == 0) ? wqb : (z == 1) ? wkb : (z == 2) ? wvb : wgb;
  const int m0 = blockIdx.y * 128;
  const int n0 = blockIdx.x * 128;

  f32x4 acc[4][4];
  gemm128_core(xb, W, m0, n0, As, Bs, acc);

  const int lane = threadIdx.x & 63;
  const int wr = (threadIdx.x >> 6) >> 1, wc = (threadIdx.x >> 6) & 1;
  const int l15 = lane & 15, l4 = lane >> 4;
  const int rbase = m0 + wr * 64 + l4 * 4;   // + m*16 + r
  const int cbase = n0 + wc * 64 + l15;      // + n*16

  if (z <= 1) {
    // RoPE: pair (dh, dh+32) lives in fragments n and n+2 of the same thread.
    u16* dst = z ? kb : qb;
    #pragma unroll
    for (int m = 0; m < 4; ++m)
      #pragma unroll
      for (int n = 0; n < 2; ++n)
        #pragma unroll
        for (int r = 0; r < 4; ++r) {
          const int row = rbase + m * 16 + r;
          const int s = row & (S_LEN - 1);
          const int dh = n * 16 + l15;               // 0..31
          const float2 cs = rope[s * 32 + dh];
          const float x1 = acc[m][n][r];
          const float x2 = acc[m][n + 2][r];
          dst[(size_t)row * D_DIM + cbase + n * 16]       = f2bf(x1 * cs.x - x2 * cs.y);
          dst[(size_t)row * D_DIM + cbase + (n + 2) * 16] = f2bf(x2 * cs.x + x1 * cs.y);
        }
  } else if (z == 2) {
    // v stored transposed: vT[(b,h,dh)][s], so retention can stage V^T linearly.
    #pragma unroll
    for (int m = 0; m < 4; ++m)
      #pragma unroll
      for (int n = 0; n < 4; ++n)
        #pragma unroll
        for (int r = 0; r < 4; ++r) {
          const int row = rbase + m * 16 + r;
          const int col = cbase + n * 16;
          const int b = row >> 11, s = row & (S_LEN - 1);
          const int h = col >> 6, dh = col & 63;
          vT[(size_t)((b * NH + h) * DH + dh) * S_LEN + s] = f2bf(acc[m][n][r]);
        }
  } else {
    // g = silu(x @ wg^T)
    #pragma unroll
    for (int m = 0; m < 4; ++m)
      #pragma unroll
      for (int n = 0; n < 4; ++n)
        #pragma unroll
        for (int r = 0; r < 4; ++r) {
          const int row = rbase + m * 16 + r;
          const int col = cbase + n * 16;
          const float v = acc[m][n][r];
          gb[(size_t)row * D_DIM + col] = f2bf(v / (1.f + __expf(-v)));
        }
  }
}

// ---------- retention: O = (decay .* (Q K^T / 8)) V, fused * g ----------
__global__ __launch_bounds__(256) void retention_kernel(
    const u16* __restrict__ qb, const u16* __restrict__ kb,
    const u16* __restrict__ vT, const u16* __restrict__ gb,
    u16* __restrict__ ob)
{
  __shared__ u16 Qs[128 * 64];     // 16 KB
  __shared__ u16 Ks[64 * 64];      //  8 KB
  __shared__ u16 Vs[64 * 64];      //  8 KB, transposed: Vs[d][t]
  __shared__ u16 Ps[4][32 * 64];   // 16 KB, per-wave P relayout buffer

  const int tid = threadIdx.x, lane = tid & 63, wid = tid >> 6;
  const int l15 = lane & 15, l4 = lane >> 4;
  const int bh = blockIdx.y, b = bh >> 4, h = bh & (NH - 1);
  const int s0 = blockIdx.x * 128;

  const float gamma = 1.f - exp2f(-5.f - (float)h);
  const float lg = log2f(gamma);   // log2(gamma) < 0

  // stage Q tile [128 x 64] once
  #pragma unroll
  for (int i = 0; i < 4; ++i) {
    int c = tid + i * 256;
    int row = c >> 3, ch = c & 7;
    gll16(qb + (size_t)(b * S_LEN + s0 + row) * D_DIM + h * DH + ch * 8, Qs + c * 8);
  }

  f32x4 acc_o[2][4];
  #pragma unroll
  for (int m = 0; m < 2; ++m)
    #pragma unroll
    for (int n = 0; n < 4; ++n)
      acc_o[m][n] = (f32x4){0.f, 0.f, 0.f, 0.f};

  const int nt = (s0 >> 6) + 2;
  for (int tt = 0; tt < nt; ++tt) {
    const int t0 = tt * 64;
    const int dmin = s0 - (t0 + 63);
    // negligible-decay tile skip (block-uniform -> barrier-safe)
    if (dmin > 0 && (float)dmin * lg < -40.f) continue;

    // stage K tile [64 x 64] and V^T tile [64 x 64]
    #pragma unroll
    for (int i = 0; i < 2; ++i) {
      int c = tid + i * 256;
      int row = c >> 3, ch = c & 7;
      gll16(kb + (size_t)(b * S_LEN + t0 + row) * D_DIM + h * DH + ch * 8, Ks + c * 8);
      gll16(vT + (size_t)(bh * DH + row) * S_LEN + t0 + ch * 8, Vs + c * 8);
    }
    __syncthreads();

    // S = Q K^T  (wave wid owns q-rows [wid*32, wid*32+32))
    f32x4 acc_s[2][4];
    #pragma unroll
    for (int m = 0; m < 2; ++m)
      #pragma unroll
      for (int n = 0; n < 4; ++n)
        acc_s[m][n] = (f32x4){0.f, 0.f, 0.f, 0.f};
    #pragma unroll
    for (int kk = 0; kk < 2; ++kk) {
      short8 av[2], bv[4];
      #pragma unroll
      for (int m = 0; m < 2; ++m)
        av[m] = *(const short8*)(Qs + (wid * 32 + m * 16 + l15) * 64 + kk * 32 + l4 * 8);
      #pragma unroll
      for (int n = 0; n < 4; ++n)
        bv[n] = *(const short8*)(Ks + (n * 16 + l15) * 64 + kk * 32 + l4 * 8);
      #pragma unroll
      for (int m = 0; m < 2; ++m)
        #pragma unroll
        for (int n = 0; n < 4; ++n)
          acc_s[m][n] = __builtin_amdgcn_mfma_f32_16x16x32_bf16(av[m], bv[n], acc_s[m][n], 0, 0, 0);
    }

    // scale + causal decay, write P as bf16 into per-wave LDS
    #pragma unroll
    for (int m = 0; m < 2; ++m)
      #pragma unroll
      for (int n = 0; n < 4; ++n)
        #pragma unroll
        for (int r = 0; r < 4; ++r) {
          const int qlocal = m * 16 + l4 * 4 + r;
          const int sg = s0 + wid * 32 + qlocal;
          const int tg = t0 + n * 16 + l15;
          const int d = sg - tg;
          float val = 0.f;
          if (d >= 0) val = acc_s[m][n][r] * 0.125f * exp2f((float)d * lg);
          Ps[wid][qlocal * 64 + n * 16 + l15] = f2bf(val);
        }
    __syncthreads();

    // O += P V   (A-frag from Ps, B-frag from transposed Vs)
    #pragma unroll
    for (int kk = 0; kk < 2; ++kk) {
      short8 av[2], bv[4];
      #pragma unroll
      for (int m = 0; m < 2; ++m)
        av[m] = *(const short8*)(&Ps[wid][(m * 16 + l15) * 64 + kk * 32 + l4 * 8]);
      #pragma unroll
      for (int n = 0; n < 4; ++n)
        bv[n] = *(const short8*)(Vs + (n * 16 + l15) * 64 + kk * 32 + l4 * 8);
      #pragma unroll
      for (int m = 0; m < 2; ++m)
        #pragma unroll
        for (int n = 0; n < 4; ++n)
          acc_o[m][n] = __builtin_amdgcn_mfma_f32_16x16x32_bf16(av[m], bv[n], acc_o[m][n], 0, 0, 0);
    }
    __syncthreads();
  }

  // epilogue: ob = O * g  (bf16)
  #pragma unroll
  for (int m = 0; m < 2; ++m)
    #pragma unroll
    for (int n = 0; n < 4; ++n)
      #pragma unroll
      for (int r = 0; r < 4; ++r) {
        const int s = s0 + wid * 32 + m * 16 + l4 * 4 + r;
        const int col = h * DH + n * 16 + l15;
        const size_t idx = (size_t)(b * S_LEN + s) * D_DIM + col;
        ob[idx] = f2bf(acc_o[m][n][r] * bf2f(gb[idx]));
      }
}

// ---------- final GEMM: out = (O .* g) @ wo^T, fp32 output ----------
__global__ __launch_bounds__(256) void final_kernel(
    const u16* __restrict__ ob, const u16* __restrict__ wob,
    float* __restrict__ out)
{
  __shared__ u16 As[128 * 64];
  __shared__ u16 Bs[128 * 64];
  const int m0 = blockIdx.y * 128, n0 = blockIdx.x * 128;
  f32x4 acc[4][4];
  gemm128_core(ob, wob, m0, n0, As, Bs, acc);

  const int lane = threadIdx.x & 63;
  const int wr = (threadIdx.x >> 6) >> 1, wc = (threadIdx.x >> 6) & 1;
  const int rbase = m0 + wr * 64 + (lane >> 4) * 4;
  const int cbase = n0 + wc * 64 + (lane & 15);
  #pragma unroll
  for (int m = 0; m < 4; ++m)
    #pragma unroll
    for (int n = 0; n < 4; ++n)
      #pragma unroll
      for (int r = 0; r < 4; ++r)
        out[(size_t)(rbase + m * 16 + r) * D_DIM + cbase + n * 16] = acc[m][n][r];
}

extern "C" void kernel_launch(void* const* d_in, const int* in_sizes, int n_in,
                              void* d_out, int out_size, void* d_ws, size_t ws_size,
                              hipStream_t stream) {
  (void)in_sizes; (void)n_in; (void)out_size; (void)ws_size;
  const float* x  = (const float*)d_in[0];
  const float* wq = (const float*)d_in[1];
  const float* wk = (const float*)d_in[2];
  const float* wv = (const float*)d_in[3];
  const float* wg = (const float*)d_in[4];
  const float* wo = (const float*)d_in[5];
  float* out = (float*)d_out;

  char* ws = (char*)d_ws;
  const size_t SZ_X = (size_t)M_ROWS * D_DIM * 2;   // 8 MB
  const size_t SZ_W = (size_t)D_DIM * D_DIM * 2;    // 2 MB
  u16* xb  = (u16*)(ws);
  u16* wqb = (u16*)(ws + SZ_X);
  u16* wkb = (u16*)(ws + SZ_X + 1 * SZ_W);
  u16* wvb = (u16*)(ws + SZ_X + 2 * SZ_W);
  u16* wgb = (u16*)(ws + SZ_X + 3 * SZ_W);
  u16* wob = (u16*)(ws + SZ_X + 4 * SZ_W);
  u16* qb  = (u16*)(ws + 1 * SZ_X + 5 * SZ_W);
  u16* kb  = (u16*)(ws + 2 * SZ_X + 5 * SZ_W);
  u16* vT  = (u16*)(ws + 3 * SZ_X + 5 * SZ_W);
  u16* gb  = (u16*)(ws + 4 * SZ_X + 5 * SZ_W);
  u16* ob  = (u16*)(ws + 5 * SZ_X + 5 * SZ_W);
  float2* rope = (float2*)(ws + 6 * SZ_X + 5 * SZ_W);
  // total workspace use: 6*8MB + 5*2MB + 0.5MB = 58.5 MB

  const int nx4 = M_ROWS * D_DIM / 4;
  const int nw4 = D_DIM * D_DIM / 4;
  cvt_bf16<<<nx4 / 256, 256, 0, stream>>>(x,  xb,  nx4);
  cvt_bf16<<<nw4 / 256, 256, 0, stream>>>(wq, wqb, nw4);
  cvt_bf16<<<nw4 / 256, 256, 0, stream>>>(wk, wkb, nw4);
  cvt_bf16<<<nw4 / 256, 256, 0, stream>>>(wv, wvb, nw4);
  cvt_bf16<<<nw4 / 256, 256, 0, stream>>>(wg, wgb, nw4);
  cvt_bf16<<<nw4 / 256, 256, 0, stream>>>(wo, wob, nw4);
  rope_tab<<<(S_LEN * 32) / 256, 256, 0, stream>>>(rope);

  proj_kernel<<<dim3(D_DIM / 128, M_ROWS / 128, 4), 256, 0, stream>>>(
      xb, wqb, wkb, wvb, wgb, qb, kb, vT, gb, rope);
  retention_kernel<<<dim3(S_LEN / 128, B_SZ * NH), 256, 0, stream>>>(
      qb, kb, vT, gb, ob);
  final_kernel<<<dim3(D_DIM / 128, M_ROWS / 128), 256, 0, stream>>>(ob, wob, out);
}

// Round 2
// 211.195 us; speedup vs baseline: 1.0684x; 1.0684x over previous
//
#include <hip/hip_runtime.h>

typedef unsigned short u16;
typedef unsigned int u32;
typedef __attribute__((ext_vector_type(8))) short short8;
typedef __attribute__((ext_vector_type(4))) float f32x4;

#define S_LEN 2048
#define D_DIM 1024
#define NH    16
#define DH    64
#define B_SZ  2
#define M_ROWS (B_SZ * S_LEN)   // 4096

// ---------- helpers ----------
__device__ __forceinline__ u16 f2bf(float f) {
  u32 u = __float_as_uint(f);
  u += 0x7FFFu + ((u >> 16) & 1u);   // RNE
  return (u16)(u >> 16);
}
__device__ __forceinline__ float bf2f(u16 u) {
  return __uint_as_float(((u32)u) << 16);
}

__device__ __forceinline__ void gll16(const void* g, void* l) {
  __builtin_amdgcn_global_load_lds((const __attribute__((address_space(1))) u32*)g,
                                   (__attribute__((address_space(3))) u32*)l,
                                   16, 0, 0);
}

// ---------- elementwise conversion fp32 -> bf16 ----------
__global__ __launch_bounds__(256) void cvt_bf16(const float* __restrict__ src,
                                                u16* __restrict__ dst, int n4) {
  int i = blockIdx.x * 256 + threadIdx.x;
  if (i >= n4) return;
  const float4 v = ((const float4*)src)[i];
  u32 lo = (u32)f2bf(v.x) | ((u32)f2bf(v.y) << 16);
  u32 hi = (u32)f2bf(v.z) | ((u32)f2bf(v.w) << 16);
  ((u32*)dst)[2 * i]     = lo;
  ((u32*)dst)[2 * i + 1] = hi;
}

// ---------- RoPE cos/sin table: tab[s][j] for j in [0,32) ----------
__global__ __launch_bounds__(256) void rope_tab(float2* __restrict__ tab) {
  int i = blockIdx.x * 256 + threadIdx.x;   // S_LEN*32 entries
  int s = i >> 5, j = i & 31;
  float inv = exp2f(-(float)j * (13.287712379549449f / 32.f)); // 10000^(-j/32)
  float fr = (float)s * inv;
  tab[i] = make_float2(cosf(fr), sinf(fr));
}

// ---------- shared 128x128-tile GEMM core: C = A[M,K] * W[N,K]^T ----------
__device__ __forceinline__ void gemm128_core(const u16* __restrict__ A,
                                             const u16* __restrict__ W,
                                             int m0, int n0,
                                             u16* As, u16* Bs,
                                             f32x4 acc[4][4]) {
  const int tid  = threadIdx.x;
  const int lane = tid & 63;
  const int wr   = (tid >> 6) >> 1;
  const int wc   = (tid >> 6) & 1;
  const int l15  = lane & 15;
  const int l4   = lane >> 4;

  #pragma unroll
  for (int m = 0; m < 4; ++m)
    #pragma unroll
    for (int n = 0; n < 4; ++n)
      acc[m][n] = (f32x4){0.f, 0.f, 0.f, 0.f};

  for (int kt = 0; kt < D_DIM / 64; ++kt) {
    const int k0 = kt * 64;
    #pragma unroll
    for (int i = 0; i < 4; ++i) {
      int c = tid + i * 256;            // chunk id: 1024 chunks of 16B per tile
      int row = c >> 3, ch = c & 7;
      gll16(A + (size_t)(m0 + row) * D_DIM + k0 + ch * 8, As + c * 8);
      gll16(W + (size_t)(n0 + row) * D_DIM + k0 + ch * 8, Bs + c * 8);
    }
    __syncthreads();
    #pragma unroll
    for (int kk = 0; kk < 2; ++kk) {
      short8 av[4], bv[4];
      #pragma unroll
      for (int m = 0; m < 4; ++m)
        av[m] = *(const short8*)(As + (wr * 64 + m * 16 + l15) * 64 + kk * 32 + l4 * 8);
      #pragma unroll
      for (int n = 0; n < 4; ++n)
        bv[n] = *(const short8*)(Bs + (wc * 64 + n * 16 + l15) * 64 + kk * 32 + l4 * 8);
      #pragma unroll
      for (int m = 0; m < 4; ++m)
        #pragma unroll
        for (int n = 0; n < 4; ++n)
          acc[m][n] = __builtin_amdgcn_mfma_f32_16x16x32_bf16(av[m], bv[n], acc[m][n], 0, 0, 0);
    }
    __syncthreads();
  }
}

// ---------- fused projection: q(+rope), k(+rope), v(->transposed), g(silu) ----------
__global__ __launch_bounds__(256) void proj_kernel(
    const u16* __restrict__ xb,
    const u16* __restrict__ wqb, const u16* __restrict__ wkb,
    const u16* __restrict__ wvb, const u16* __restrict__ wgb,
    u16* __restrict__ qb, u16* __restrict__ kb,
    u16* __restrict__ vT, u16* __restrict__ gb,
    const float2* __restrict__ rope)
{
  __shared__ u16 As[128 * 64];
  __shared__ u16 Bs[128 * 64];
  const int z  = blockIdx.z;
  const u16* W = (z == 0) ? wqb : (z == 1) ? wkb : (z == 2) ? wvb : wgb;
  const int m0 = blockIdx.y * 128;
  const int n0 = blockIdx.x * 128;

  f32x4 acc[4][4];
  gemm128_core(xb, W, m0, n0, As, Bs, acc);

  const int lane = threadIdx.x & 63;
  const int wr = (threadIdx.x >> 6) >> 1, wc = (threadIdx.x >> 6) & 1;
  const int l15 = lane & 15, l4 = lane >> 4;
  const int rbase = m0 + wr * 64 + l4 * 4;
  const int cbase = n0 + wc * 64 + l15;

  if (z <= 1) {
    u16* dst = z ? kb : qb;
    #pragma unroll
    for (int m = 0; m < 4; ++m)
      #pragma unroll
      for (int n = 0; n < 2; ++n)
        #pragma unroll
        for (int r = 0; r < 4; ++r) {
          const int row = rbase + m * 16 + r;
          const int s = row & (S_LEN - 1);
          const int dh = n * 16 + l15;
          const float2 cs = rope[s * 32 + dh];
          const float x1 = acc[m][n][r];
          const float x2 = acc[m][n + 2][r];
          dst[(size_t)row * D_DIM + cbase + n * 16]       = f2bf(x1 * cs.x - x2 * cs.y);
          dst[(size_t)row * D_DIM + cbase + (n + 2) * 16] = f2bf(x2 * cs.x + x1 * cs.y);
        }
  } else if (z == 2) {
    #pragma unroll
    for (int m = 0; m < 4; ++m)
      #pragma unroll
      for (int n = 0; n < 4; ++n)
        #pragma unroll
        for (int r = 0; r < 4; ++r) {
          const int row = rbase + m * 16 + r;
          const int col = cbase + n * 16;
          const int b = row >> 11, s = row & (S_LEN - 1);
          const int h = col >> 6, dh = col & 63;
          vT[(size_t)((b * NH + h) * DH + dh) * S_LEN + s] = f2bf(acc[m][n][r]);
        }
  } else {
    #pragma unroll
    for (int m = 0; m < 4; ++m)
      #pragma unroll
      for (int n = 0; n < 4; ++n)
        #pragma unroll
        for (int r = 0; r < 4; ++r) {
          const int row = rbase + m * 16 + r;
          const int col = cbase + n * 16;
          const float v = acc[m][n][r];
          gb[(size_t)row * D_DIM + col] = f2bf(v / (1.f + __expf(-v)));
        }
  }
}

// ---------- retention v2: t-split jobs, K/V global->reg, 0 loop barriers ----------
// job = (bh, qtile, chunk of <=8 k-tiles); partial O accumulated via atomicAdd f32.
__global__ __launch_bounds__(256) void retention_kernel(
    const u16* __restrict__ qb, const u16* __restrict__ kb,
    const u16* __restrict__ vT, float* __restrict__ obf)
{
  __shared__ u16 Qs[128 * 64];     // 16 KB, swizzled chunks
  __shared__ u16 Ps[4][32 * 64];   // 16 KB, per-wave, swizzled

  const int tid = threadIdx.x, lane = tid & 63, wid = tid >> 6;
  const int l15 = lane & 15, l4 = lane >> 4;

  // ---- job decode: 40 jobs per (b,h) ----
  int job = blockIdx.x;
  const int bh = job / 40; job -= bh * 40;
  const int b = bh >> 4, h = bh & (NH - 1);
  int qtile = 0, chunk = job;
  while (true) { int cnt = (qtile >> 2) + 1; if (chunk < cnt) break; chunk -= cnt; ++qtile; }
  const int s0 = qtile * 128;
  const int nt = 2 * qtile + 2;
  const int tstart = chunk * 8;
  const int tend = (tstart + 8 < nt) ? (tstart + 8) : nt;

  const float gamma = 1.f - exp2f(-5.f - (float)h);
  const float lg = log2f(gamma);   // < 0

  // whole-chunk negligible -> exit (block-uniform)
  {
    const int dlast = s0 - ((tend - 1) * 64 + 63);
    if (dlast > 0 && (float)dlast * lg < -30.f) return;
  }

  // ---- per-wave Q stage (each wave stages exactly its own 32 rows) ----
  #pragma unroll
  for (int i = 0; i < 4; ++i) {
    const int c = wid * 256 + i * 64 + lane;
    const int row = c >> 3, ch = c & 7;
    const int sch = ch ^ (row & 7);   // pre-swizzled source chunk (rule 21)
    gll16(qb + (size_t)(b * S_LEN + s0 + row) * D_DIM + h * DH + sch * 8, Qs + c * 8);
  }
  __syncthreads();   // drains vmcnt; Q ready

  // Q fragments hoisted to registers (loop-invariant)
  short8 qf[2][2];
  #pragma unroll
  for (int m = 0; m < 2; ++m)
    #pragma unroll
    for (int kk = 0; kk < 2; ++kk) {
      const int row = wid * 32 + m * 16 + l15;
      qf[m][kk] = *(const short8*)(Qs + row * 64 + (((kk * 4 + l4) ^ (row & 7)) << 3));
    }

  // decay row factor: exp2((sg - s0) * lg), loop-invariant
  float Ea[2][4];
  #pragma unroll
  for (int m = 0; m < 2; ++m)
    #pragma unroll
    for (int r = 0; r < 4; ++r)
      Ea[m][r] = exp2f((float)(wid * 32 + m * 16 + l4 * 4 + r) * lg);

  f32x4 acc_o[2][4];
  #pragma unroll
  for (int m = 0; m < 2; ++m)
    #pragma unroll
    for (int n = 0; n < 4; ++n)
      acc_o[m][n] = (f32x4){0.f, 0.f, 0.f, 0.f};

  for (int tt = tstart; tt < tend; ++tt) {
    const int t0 = tt * 64;
    const int dmin = s0 - (t0 + 63);
    if (dmin > 0 && (float)dmin * lg < -30.f) continue;   // per-wave safe: no barriers

    // K fragments: global -> reg (L2-resident)
    short8 kf[2][4];
    #pragma unroll
    for (int kk = 0; kk < 2; ++kk)
      #pragma unroll
      for (int n = 0; n < 4; ++n)
        kf[kk][n] = *(const short8*)(kb + (size_t)(b * S_LEN + t0 + n * 16 + l15) * D_DIM
                                        + h * DH + kk * 32 + l4 * 8);

    // S = Q K^T
    f32x4 acc_s[2][4];
    #pragma unroll
    for (int m = 0; m < 2; ++m)
      #pragma unroll
      for (int n = 0; n < 4; ++n)
        acc_s[m][n] = (f32x4){0.f, 0.f, 0.f, 0.f};
    #pragma unroll
    for (int kk = 0; kk < 2; ++kk)
      #pragma unroll
      for (int m = 0; m < 2; ++m)
        #pragma unroll
        for (int n = 0; n < 4; ++n)
          acc_s[m][n] = __builtin_amdgcn_mfma_f32_16x16x32_bf16(qf[m][kk], kf[kk][n], acc_s[m][n], 0, 0, 0);

    // V fragments: issue early so HBM/L2 latency hides under decay+Ps phase
    short8 vf[2][4];
    #pragma unroll
    for (int kk = 0; kk < 2; ++kk)
      #pragma unroll
      for (int n = 0; n < 4; ++n)
        vf[kk][n] = *(const short8*)(vT + (size_t)(bh * DH + n * 16 + l15) * S_LEN
                                        + t0 + kk * 32 + l4 * 8);

    // decay column factor: exp2((s0 - tg) * lg)
    float Eb[4];
    #pragma unroll
    for (int n = 0; n < 4; ++n)
      Eb[n] = exp2f((float)(s0 - (t0 + n * 16 + l15)) * lg);

    // scale + causal decay, write P bf16 into per-wave swizzled LDS (no barrier)
    #pragma unroll
    for (int m = 0; m < 2; ++m)
      #pragma unroll
      for (int n = 0; n < 4; ++n)
        #pragma unroll
        for (int r = 0; r < 4; ++r) {
          const int qlocal = m * 16 + l4 * 4 + r;
          const int sg = s0 + wid * 32 + qlocal;
          const int tg = t0 + n * 16 + l15;
          const float val = (sg >= tg) ? acc_s[m][n][r] * 0.125f * Ea[m][r] * Eb[n] : 0.f;
          const int col = n * 16 + l15;
          Ps[wid][qlocal * 64 + (((col >> 3) ^ (qlocal & 7)) << 3) + (col & 7)] = f2bf(val);
        }

    // O += P V  (Ps per-wave: same-wave lgkmcnt ordering, no __syncthreads)
    #pragma unroll
    for (int kk = 0; kk < 2; ++kk) {
      short8 pf[2];
      #pragma unroll
      for (int m = 0; m < 2; ++m) {
        const int row = m * 16 + l15;
        pf[m] = *(const short8*)(&Ps[wid][row * 64 + (((kk * 4 + l4) ^ (row & 7)) << 3)]);
      }
      #pragma unroll
      for (int m = 0; m < 2; ++m)
        #pragma unroll
        for (int n = 0; n < 4; ++n)
          acc_o[m][n] = __builtin_amdgcn_mfma_f32_16x16x32_bf16(pf[m], vf[kk][n], acc_o[m][n], 0, 0, 0);
    }
  }

  // partial-O accumulate
  #pragma unroll
  for (int m = 0; m < 2; ++m)
    #pragma unroll
    for (int n = 0; n < 4; ++n)
      #pragma unroll
      for (int r = 0; r < 4; ++r) {
        const int s = s0 + wid * 32 + m * 16 + l4 * 4 + r;
        const int col = h * DH + n * 16 + l15;
        atomicAdd(&obf[(size_t)(b * S_LEN + s) * D_DIM + col], acc_o[m][n][r]);
      }
}

// ---------- fuse: ob = bf16(obf * g) ----------
__global__ __launch_bounds__(256) void fuse_og(const float* __restrict__ obf,
                                               const u16* __restrict__ gb,
                                               u16* __restrict__ ob, int n8) {
  int i = blockIdx.x * 256 + threadIdx.x;
  if (i >= n8) return;
  const float4 a0 = ((const float4*)obf)[2 * i];
  const float4 a1 = ((const float4*)obf)[2 * i + 1];
  const short8 g = ((const short8*)gb)[i];
  float av[8] = {a0.x, a0.y, a0.z, a0.w, a1.x, a1.y, a1.z, a1.w};
  short8 out;
  #pragma unroll
  for (int j = 0; j < 8; ++j)
    out[j] = (short)f2bf(av[j] * bf2f((u16)g[j]));
  ((short8*)ob)[i] = out;
}

// ---------- final GEMM: out = (O .* g) @ wo^T, fp32 output ----------
__global__ __launch_bounds__(256) void final_kernel(
    const u16* __restrict__ ob, const u16* __restrict__ wob,
    float* __restrict__ out)
{
  __shared__ u16 As[128 * 64];
  __shared__ u16 Bs[128 * 64];
  const int m0 = blockIdx.y * 128, n0 = blockIdx.x * 128;
  f32x4 acc[4][4];
  gemm128_core(ob, wob, m0, n0, As, Bs, acc);

  const int lane = threadIdx.x & 63;
  const int wr = (threadIdx.x >> 6) >> 1, wc = (threadIdx.x >> 6) & 1;
  const int rbase = m0 + wr * 64 + (lane >> 4) * 4;
  const int cbase = n0 + wc * 64 + (lane & 15);
  #pragma unroll
  for (int m = 0; m < 4; ++m)
    #pragma unroll
    for (int n = 0; n < 4; ++n)
      #pragma unroll
      for (int r = 0; r < 4; ++r)
        out[(size_t)(rbase + m * 16 + r) * D_DIM + cbase + n * 16] = acc[m][n][r];
}

extern "C" void kernel_launch(void* const* d_in, const int* in_sizes, int n_in,
                              void* d_out, int out_size, void* d_ws, size_t ws_size,
                              hipStream_t stream) {
  (void)in_sizes; (void)n_in; (void)out_size; (void)ws_size;
  const float* x  = (const float*)d_in[0];
  const float* wq = (const float*)d_in[1];
  const float* wk = (const float*)d_in[2];
  const float* wv = (const float*)d_in[3];
  const float* wg = (const float*)d_in[4];
  const float* wo = (const float*)d_in[5];
  float* out = (float*)d_out;

  char* ws = (char*)d_ws;
  const size_t SZ_X = (size_t)M_ROWS * D_DIM * 2;   // 8 MB
  const size_t SZ_W = (size_t)D_DIM * D_DIM * 2;    // 2 MB
  u16* xb  = (u16*)(ws);
  u16* wqb = (u16*)(ws + SZ_X);
  u16* wkb = (u16*)(ws + SZ_X + 1 * SZ_W);
  u16* wvb = (u16*)(ws + SZ_X + 2 * SZ_W);
  u16* wgb = (u16*)(ws + SZ_X + 3 * SZ_W);
  u16* wob = (u16*)(ws + SZ_X + 4 * SZ_W);
  u16* qb  = (u16*)(ws + 1 * SZ_X + 5 * SZ_W);
  u16* kb  = (u16*)(ws + 2 * SZ_X + 5 * SZ_W);
  u16* vT  = (u16*)(ws + 3 * SZ_X + 5 * SZ_W);
  u16* gb  = (u16*)(ws + 4 * SZ_X + 5 * SZ_W);
  u16* ob  = (u16*)(ws + 5 * SZ_X + 5 * SZ_W);
  float2* rope = (float2*)(ws + 6 * SZ_X + 5 * SZ_W);
  // obf (fp32, 16MB) aliases xb..wgb — all dead after proj_kernel. wob untouched.
  float* obf = (float*)(ws);

  const int nx4 = M_ROWS * D_DIM / 4;
  const int nw4 = D_DIM * D_DIM / 4;
  cvt_bf16<<<nx4 / 256, 256, 0, stream>>>(x,  xb,  nx4);
  cvt_bf16<<<nw4 / 256, 256, 0, stream>>>(wq, wqb, nw4);
  cvt_bf16<<<nw4 / 256, 256, 0, stream>>>(wk, wkb, nw4);
  cvt_bf16<<<nw4 / 256, 256, 0, stream>>>(wv, wvb, nw4);
  cvt_bf16<<<nw4 / 256, 256, 0, stream>>>(wg, wgb, nw4);
  cvt_bf16<<<nw4 / 256, 256, 0, stream>>>(wo, wob, nw4);
  rope_tab<<<(S_LEN * 32) / 256, 256, 0, stream>>>(rope);

  proj_kernel<<<dim3(D_DIM / 128, M_ROWS / 128, 4), 256, 0, stream>>>(
      xb, wqb, wkb, wvb, wgb, qb, kb, vT, gb, rope);

  hipMemsetAsync(obf, 0, (size_t)M_ROWS * D_DIM * sizeof(float), stream);

  retention_kernel<<<dim3(40 * B_SZ * NH), 256, 0, stream>>>(qb, kb, vT, obf);

  fuse_og<<<(M_ROWS * D_DIM / 8 + 255) / 256, 256, 0, stream>>>(
      obf, gb, ob, M_ROWS * D_DIM / 8);

  final_kernel<<<dim3(D_DIM / 128, M_ROWS / 128), 256, 0, stream>>>(ob, wob, out);
}